// Round 18
// baseline (21.789 us; speedup 1.0000x reference)
//
#include <hip/hip_runtime.h>
#include <math.h>

// DMLoss fused kernel for MI355X (gfx950).
// Round 18: merge-free role-split blocks. All prior nulls point at lockstep
// phase alignment + LDS merge micro-phases. Now: argmin completes within a
// 2-4 lane group via __shfl_xor u64-min (packed (d_bits<<32)|idx keys, exact
// first-occurrence); zero merge phases, 2 barriers. Phase B blocks (2048:
// 64 pts x 4-way split, 32 rolling-D iters) and Phase C blocks (1024: 128 pts
// x 2-way split, 64 iters) are duration-balanced; 3072 blocks oversubscribe
// 8-resident/CU -> queue slack + free wave drift. Scan math identical to R16.

#define BB 1024
#define NN 128
#define MM 128

typedef unsigned long long u64;
typedef unsigned int u32;

__device__ __forceinline__ float sl1(float x) {
    float d = fabsf(x);
    return d < 1.0f ? 0.5f * d * d : d - 0.5f;
}

__global__ void __launch_bounds__(256, 8)
dmloss_main(const float* __restrict__ ini, const float* __restrict__ pred,
            const float* __restrict__ gt,  const float* __restrict__ kmask,
            float* __restrict__ pA, float2* __restrict__ pBC)
{
    const int bid = blockIdx.x;
    const int tid = threadIdx.x;

    __shared__ float4 s_seg[MM];     // B: (gx, gy, 5/|e|^2, |e|^2/100)
    __shared__ float  s_step[16];    // B: exact j/10
    __shared__ float2 s_ii[NN];      // C: ini points
    __shared__ float2 s_pr[NN];      // C: pred points
    __shared__ float  s_sum[2][4];
    const int wave = tid >> 6;

    if (bid < 2 * BB) {
        // ================= Phase B block =================
        const int b    = bid >> 1;
        const int half = bid & 1;              // points [64*half, 64*half+64)
        const int q    = tid & 3;              // 4-way segment split
        const int P    = (half << 6) + (tid >> 2);

        const float2* gt2 = (const float2*)(gt  + (size_t)b * MM * 2);
        const float2* in2 = (const float2*)(ini + (size_t)b * NN * 2);
        const float2* pr2 = (const float2*)(pred + (size_t)b * NN * 2);

        if (tid < 128) {
            int m = tid;
            float2 gm = gt2[m];
            float2 a  = gt2[(m + 127) & 127];
            float ex = gm.x - a.x, ey = gm.y - a.y;
            float A  = ex * ex + ey * ey;
            float inv5 = A > 0.f ? 5.f / A : 0.f;  // degenerate: jv=5,E=0 -> d=Da
            s_seg[m] = make_float4(gm.x, gm.y, inv5, A * 0.01f);
            if (tid < 16) s_step[tid] = (float)tid / 10.0f;
        }
        float2 myP  = in2[P];                  // group-shared (L1 broadcast)
        float2 myPr = make_float2(0.f, 0.f);
        if (q == 0) myPr = pr2[P];
        const float px = myP.x, py = myP.y;
        __syncthreads();

        // rolling-D scan over segments [32q, 32q+32)  (bit-identical to R16)
        u64 best = ~0ull;
        {
            const int m0 = 32 * q;
            float2 a0 = make_float2(s_seg[(m0 + 127) & 127].x,
                                    s_seg[(m0 + 127) & 127].y);
            float dax = a0.x - px, day = a0.y - py;
            float Da = fmaf(day, day, dax * dax);
            int bi = 10 * m0;
            #pragma unroll 4
            for (int j = 0; j < 32; ++j) {
                float4 S = s_seg[m0 + j];
                float dgx = S.x - px, dgy = S.y - py;
                float Dg  = fmaf(dgy, dgy, dgx * dgx);
                float jv  = fmaf(Da - Dg, S.z, 5.0f);
                float jr  = rintf(__builtin_amdgcn_fmed3f(jv, 0.f, 9.f));
                float t   = fmaf(jv, -2.f, jr);
                float d   = fmaf(S.w * jr, t, Da);
                u64 c = ((u64)__builtin_bit_cast(u32, d) << 32)
                        | (u32)(bi + (int)jr);
                if (c < best) best = c;        // u64 min = exact first-occ.
                Da = Dg;
                bi += 10;
            }
        }
        // 4-lane butterfly min (no LDS, no barrier)
        { u64 o = __shfl_xor(best, 1); if (o < best) best = o; }
        { u64 o = __shfl_xor(best, 2); if (o < best) best = o; }

        float sumA = 0.f;
        if (q == 0) {
            u32 idx = (u32)best;
            int m = (int)idx / 10;
            int j = (int)idx - 10 * m;
            float s  = s_step[j];
            float tt = 1.0f - s;
            float4 Sm = s_seg[m];
            float4 Sp = s_seg[(m + 127) & 127];
            float gx = Sm.x * s + Sp.x * tt;   // exact reference interp formula
            float gy = Sm.y * s + Sp.y * tt;
            sumA = sl1(myPr.x - gx) + sl1(myPr.y - gy);
        }
        #pragma unroll
        for (int off = 32; off > 0; off >>= 1) sumA += __shfl_down(sumA, off);
        if ((tid & 63) == 0) s_sum[0][wave] = sumA;
        __syncthreads();
        if (tid == 0)
            pA[bid] = s_sum[0][0] + s_sum[0][1] + s_sum[0][2] + s_sum[0][3];
    } else {
        // ================= Phase C block =================
        const int b = bid - 2 * BB;
        const int q = tid & 1;                 // 2-way ini split
        const int m = tid >> 1;                // owned gt point

        const float2* gt2 = (const float2*)(gt  + (size_t)b * MM * 2);
        const float2* in2 = (const float2*)(ini + (size_t)b * NN * 2);
        const float2* pr2 = (const float2*)(pred + (size_t)b * NN * 2);

        if (tid < 128) {
            s_ii[tid] = in2[tid];
            s_pr[tid] = pr2[tid];
        }
        float2 myG = gt2[m];                   // pair-shared (L1 broadcast)
        float  myKm = 0.f;
        if (q == 0) myKm = kmask[b * MM + m];
        const float gx = myG.x, gy = myG.y;
        __syncthreads();

        u64 best = ~0ull;
        {
            const int k0 = 64 * q;
            #pragma unroll 4
            for (int j = 0; j < 64; ++j) {
                float2 I = s_ii[k0 + j];
                float dx = I.x - gx, dy = I.y - gy;
                float d  = fmaf(dy, dy, dx * dx);
                u64 c = ((u64)__builtin_bit_cast(u32, d) << 32)
                        | (u32)(k0 + j);
                if (c < best) best = c;
            }
        }
        { u64 o = __shfl_xor(best, 1); if (o < best) best = o; }

        float sumB = 0.f, sumC = 0.f;
        if (q == 0) {
            u32 k = (u32)best;
            float2 pk = s_pr[k];
            sumB = myKm * (sl1(pk.x - gx) + sl1(pk.y - gy));
            sumC = myKm;
        }
        #pragma unroll
        for (int off = 32; off > 0; off >>= 1) {
            sumB += __shfl_down(sumB, off);
            sumC += __shfl_down(sumC, off);
        }
        if ((tid & 63) == 0) { s_sum[0][wave] = sumB; s_sum[1][wave] = sumC; }
        __syncthreads();
        if (tid == 0)
            pBC[b] = make_float2(s_sum[0][0] + s_sum[0][1] + s_sum[0][2] + s_sum[0][3],
                                 s_sum[1][0] + s_sum[1][1] + s_sum[1][2] + s_sum[1][3]);
    }
}

__global__ void __launch_bounds__(256)
dmloss_final(const float* __restrict__ pA, const float2* __restrict__ pBC,
             float* __restrict__ out)
{
    const int tid = threadIdx.x;
    float A = 0.0f, Bs = 0.0f, C = 0.0f;
    #pragma unroll
    for (int i = tid; i < 2 * BB; i += 256) A += pA[i];
    #pragma unroll
    for (int i = tid; i < BB; i += 256) {
        float2 p = pBC[i];
        Bs += p.x; C += p.y;
    }
    #pragma unroll
    for (int off = 32; off > 0; off >>= 1) {
        A  += __shfl_down(A, off);
        Bs += __shfl_down(Bs, off);
        C  += __shfl_down(C, off);
    }
    __shared__ float sA[4], sB[4], sC[4];
    const int wave = tid >> 6, lane = tid & 63;
    if (lane == 0) { sA[wave] = A; sB[wave] = Bs; sC[wave] = C; }
    __syncthreads();
    if (tid == 0) {
        float a  = sA[0] + sA[1] + sA[2] + sA[3];
        float bs = sB[0] + sB[1] + sB[2] + sB[3];
        float c  = sC[0] + sC[1] + sC[2] + sC[3];
        float loss_pred2gt = a / ((float)BB * (float)NN * 2.0f);
        float loss_set2set = bs / (2.0f * c + 1.0f) + loss_pred2gt;
        out[0] = 0.5f * loss_set2set;
    }
}

extern "C" void kernel_launch(void* const* d_in, const int* in_sizes, int n_in,
                              void* d_out, int out_size, void* d_ws, size_t ws_size,
                              hipStream_t stream)
{
    const float* ini   = (const float*)d_in[0];
    const float* pred  = (const float*)d_in[1];
    const float* gt    = (const float*)d_in[2];
    const float* kmask = (const float*)d_in[3];

    float*  pA  = (float*)d_ws;                // [2048]
    float2* pBC = (float2*)(pA + 2 * BB);      // [1024]

    dmloss_main<<<dim3(3 * BB), dim3(256), 0, stream>>>(ini, pred, gt, kmask,
                                                        pA, pBC);
    dmloss_final<<<dim3(1), dim3(256), 0, stream>>>(pA, pBC, (float*)d_out);
}